// Round 1
// baseline (180.893 us; speedup 1.0000x reference)
//
#include <hip/hip_runtime.h>
#include <math.h>

// PizzaBurningEffect: out = clip(img*(1-bm) + img*dark_scale*bm, 0, 1)
// bm = clip(max(ew_norm, max_s spot_s) * burn, 0, 1), shared across C=3 channels.
// Memory-bound: 201 MB min traffic -> ~32 us @ 6.3 TB/s.

namespace {
constexpr int B = 32, C = 3, H = 512, W = 512, S = 8;
constexpr int PLANE = H * W;                 // 262144
constexpr int F4_PER_PLANE = PLANE / 4;      // 65536 float4 per channel-plane
constexpr int BLOCKS_PER_BATCH = F4_PER_PLANE / 256;  // 256 blocks of 256 threads
constexpr float LOG2E = 1.4426950408889634f;
}

__global__ __launch_bounds__(256) void pizza_burn_kernel(
    const float* __restrict__ img,
    const float* __restrict__ u_xy,
    const float* __restrict__ u_radius,
    const float* __restrict__ u_intensity,
    const float* __restrict__ u_burn,
    float* __restrict__ out,
    const float ew_min, const float inv_range)
{
  // b is wave-uniform (derived from blockIdx only) -> spot params scalarize.
  const int b    = blockIdx.x >> 8;                       // 256 blocks per batch
  const int pix4 = ((blockIdx.x & 255) << 8) | threadIdx.x; // 0..65535
  const int h    = pix4 >> 7;            // 128 float4 per row of 512
  const int w0   = (pix4 & 127) << 2;    // starting column of this float4

  const float delta = 2.0f / 511.0f;
  const float yc = fmaf((float)h, delta, -1.0f);
  const float y2 = yc * yc;

  // Per-batch spot parameters (uniform across the block -> scalar loads).
  const float* uxy = u_xy        + (size_t)b * S * 2;
  const float* urd = u_radius    + (size_t)b * S;
  const float* uin = u_intensity + (size_t)b * S;
  float sx[S], sy[S], nc[S], si[S];
#pragma unroll
  for (int s = 0; s < S; ++s) {
    sx[s] = fmaf(2.0f, uxy[2 * s + 0], -1.0f);
    sy[s] = fmaf(2.0f, uxy[2 * s + 1], -1.0f);
    const float r = fmaf(0.15f, urd[s], 0.05f);
    nc[s] = -LOG2E / (2.0f * r * r);            // exp(-d2/(2r^2)) = exp2(d2*nc)
    si[s] = fmaf(0.5f, uin[s], 0.5f);
  }
  const float burn = fmaf(0.6f, u_burn[b], 0.2f);  // BURN_MIN + 0.6*u

  // Burn mask for 4 consecutive pixels (same row), reused across 3 channels.
  float bm[4];
#pragma unroll
  for (int j = 0; j < 4; ++j) {
    const float xc = fmaf((float)(w0 + j), delta, -1.0f);
    const float dist = sqrtf(fmaf(xc, xc, y2));
    const float ew  = exp2f((dist - 0.7f) * (2.0f * LOG2E));
    const float ewn = (ew - ew_min) * inv_range;
    float spots = 0.0f;
#pragma unroll
    for (int s = 0; s < S; ++s) {
      const float dx = xc - sx[s];
      const float dy = yc - sy[s];
      const float d2 = fmaf(dx, dx, dy * dy);
      const float m  = exp2f(d2 * nc[s]) * si[s];
      spots = fmaxf(spots, m);
    }
    bm[j] = fminf(fmaxf(fmaxf(ewn, spots) * burn, 0.0f), 1.0f);
  }

  // out = clip(img * (1 - bm*(1-ds_c)), 0, 1), vectorized float4 per channel.
  const float omds[3] = {1.0f - 0.7f, 1.0f - 0.4f, 1.0f - 0.3f};
  const size_t base = (size_t)b * (C * PLANE) + (size_t)h * W + w0;
#pragma unroll
  for (int c = 0; c < C; ++c) {
    const float4 v = *reinterpret_cast<const float4*>(img + base + (size_t)c * PLANE);
    float4 o;
    const float k = omds[c];
    o.x = fminf(fmaxf(v.x * fmaf(-bm[0], k, 1.0f), 0.0f), 1.0f);
    o.y = fminf(fmaxf(v.y * fmaf(-bm[1], k, 1.0f), 0.0f), 1.0f);
    o.z = fminf(fmaxf(v.z * fmaf(-bm[2], k, 1.0f), 0.0f), 1.0f);
    o.w = fminf(fmaxf(v.w * fmaf(-bm[3], k, 1.0f), 0.0f), 1.0f);
    *reinterpret_cast<float4*>(out + base + (size_t)c * PLANE) = o;
  }
}

extern "C" void kernel_launch(void* const* d_in, const int* in_sizes, int n_in,
                              void* d_out, int out_size, void* d_ws, size_t ws_size,
                              hipStream_t stream) {
  const float* img         = (const float*)d_in[0];
  const float* u_xy        = (const float*)d_in[1];
  const float* u_radius    = (const float*)d_in[2];
  const float* u_intensity = (const float*)d_in[3];
  const float* u_burn      = (const float*)d_in[4];
  float* out = (float*)d_out;

  // ew min/max analytic: exp is monotone in dist.
  // min dist at grid point (±1/511, ±1/511) (linspace(-1,1,512) around 0),
  // max at the exact corners (±1, ±1).
  const float delta = 2.0f / 511.0f;
  const float cmin  = fabsf(-1.0f + 255.0f * delta);     // ~= 1/511 in f32 linspace arithmetic
  const float dmin  = sqrtf(cmin * cmin + cmin * cmin);
  const float dmax  = sqrtf(2.0f);
  const float ew_min = expf(2.0f * (dmin - 0.7f));
  const float ew_max = expf(2.0f * (dmax - 0.7f));
  const float inv_range = 1.0f / (ew_max - ew_min + 1e-6f);

  dim3 grid(B * BLOCKS_PER_BATCH);  // 8192 blocks
  dim3 block(256);
  pizza_burn_kernel<<<grid, block, 0, stream>>>(img, u_xy, u_radius, u_intensity,
                                                u_burn, out, ew_min, inv_range);
}

// Round 4
// 180.557 us; speedup vs baseline: 1.0019x; 1.0019x over previous
//
#include <hip/hip_runtime.h>
#include <math.h>

// PizzaBurningEffect: out = clip(img * (1 - bm*(1-dark_scale_c)), 0, 1)
// bm = clip(max(ew_norm, max_s spot_s) * burn, 0, 1), shared across C=3 channels.
// Memory-bound: 201 MB min traffic -> ~30 us @ 6.8 TB/s (demonstrated by harness fills).
// Spot max computed in log2 domain: max_s exp2(d2*nc_s)*si_s
//   = exp2(max_s (d2*nc_s + log2(si_s)))  -> 1 exp2/pixel instead of 8.

namespace {
constexpr int B = 32, C = 3, H = 512, W = 512, S = 8;
constexpr int PLANE = H * W;                           // 262144
constexpr int BLOCKS_PER_BATCH = PLANE / 4 / 256;      // 256 blocks of 256 threads
constexpr float LOG2E = 1.4426950408889634f;
typedef float fvec4 __attribute__((ext_vector_type(4)));  // native vector: ok for nontemporal builtins
}

__global__ __launch_bounds__(256) void pizza_burn_kernel(
    const float* __restrict__ img,
    const float* __restrict__ u_xy,
    const float* __restrict__ u_radius,
    const float* __restrict__ u_intensity,
    const float* __restrict__ u_burn,
    float* __restrict__ out,
    const float ew_scale, const float ew_bias)
{
  // b is wave-uniform (derived from blockIdx only) -> spot params scalarize.
  const int b    = blockIdx.x >> 8;                         // 256 blocks per batch
  const int pix4 = ((blockIdx.x & 255) << 8) | threadIdx.x; // 0..65535
  const int h    = pix4 >> 7;             // 128 float4 per row of 512
  const int w0   = (pix4 & 127) << 2;     // starting column of this float4

  const float delta = 2.0f / 511.0f;
  const float yc = fmaf((float)h, delta, -1.0f);
  const float y2 = yc * yc;

  // Per-batch spot parameters (uniform across the block -> scalar loads).
  const float* uxy = u_xy        + (size_t)b * S * 2;
  const float* urd = u_radius    + (size_t)b * S;
  const float* uin = u_intensity + (size_t)b * S;
  float sx[S], sy[S], nc[S], lsi[S];
#pragma unroll
  for (int s = 0; s < S; ++s) {
    sx[s] = fmaf(2.0f, uxy[2 * s + 0], -1.0f);
    sy[s] = fmaf(2.0f, uxy[2 * s + 1], -1.0f);
    const float r = fmaf(0.15f, urd[s], 0.05f);
    nc[s]  = -LOG2E / (2.0f * r * r);                  // exp(-d2/(2r^2)) = exp2(d2*nc)
    lsi[s] = __builtin_amdgcn_logf(fmaf(0.5f, uin[s], 0.5f));  // log2(si), si in [0.5,1]
  }
  const float burn = fmaf(0.6f, u_burn[b], 0.2f);      // BURN_MIN + 0.6*u

  // Burn mask for 4 consecutive pixels (same row), reused across 3 channels.
  float bm[4];
#pragma unroll
  for (int j = 0; j < 4; ++j) {
    const float xc   = fmaf((float)(w0 + j), delta, -1.0f);
    const float dist = __builtin_amdgcn_sqrtf(fmaf(xc, xc, y2));
    const float ew   = __builtin_amdgcn_exp2f(fmaf(dist, 2.0f * LOG2E, -1.4f * LOG2E));
    const float ewn  = fmaf(ew, ew_scale, ew_bias);    // (ew - ew_min) * inv_range
    float lm = -3.0e38f;
#pragma unroll
    for (int s = 0; s < S; ++s) {
      const float dx = xc - sx[s];
      const float dy = yc - sy[s];
      const float d2 = fmaf(dx, dx, dy * dy);
      lm = fmaxf(lm, fmaf(d2, nc[s], lsi[s]));         // log2(exp2(d2*nc)*si)
    }
    const float spots = __builtin_amdgcn_exp2f(lm);
    bm[j] = fminf(fmaxf(fmaxf(ewn, spots) * burn, 0.0f), 1.0f);
  }

  // out = clip(img * (1 - bm*(1-ds_c)), 0, 1), vectorized 16B per channel.
  const float omds[3] = {1.0f - 0.7f, 1.0f - 0.4f, 1.0f - 0.3f};
  const size_t base = (size_t)b * (C * PLANE) + (size_t)h * W + w0;
#pragma unroll
  for (int c = 0; c < C; ++c) {
    const fvec4 v = *reinterpret_cast<const fvec4*>(img + base + (size_t)c * PLANE);
    fvec4 o;
    const float k = omds[c];
    o.x = fminf(fmaxf(v.x * fmaf(-bm[0], k, 1.0f), 0.0f), 1.0f);
    o.y = fminf(fmaxf(v.y * fmaf(-bm[1], k, 1.0f), 0.0f), 1.0f);
    o.z = fminf(fmaxf(v.z * fmaf(-bm[2], k, 1.0f), 0.0f), 1.0f);
    o.w = fminf(fmaxf(v.w * fmaf(-bm[3], k, 1.0f), 0.0f), 1.0f);
    __builtin_nontemporal_store(o, reinterpret_cast<fvec4*>(out + base + (size_t)c * PLANE));
  }
}

extern "C" void kernel_launch(void* const* d_in, const int* in_sizes, int n_in,
                              void* d_out, int out_size, void* d_ws, size_t ws_size,
                              hipStream_t stream) {
  const float* img         = (const float*)d_in[0];
  const float* u_xy        = (const float*)d_in[1];
  const float* u_radius    = (const float*)d_in[2];
  const float* u_intensity = (const float*)d_in[3];
  const float* u_burn      = (const float*)d_in[4];
  float* out = (float*)d_out;

  // ew min/max analytic: exp is monotone in dist.
  // min dist at grid point (±1/511, ±1/511), max at the corners (±1, ±1).
  const float delta = 2.0f / 511.0f;
  const float cmin  = fabsf(-1.0f + 255.0f * delta);   // ~= 1/511 in f32 linspace arithmetic
  const float dmin  = sqrtf(2.0f * cmin * cmin);
  const float dmax  = sqrtf(2.0f);
  const float ew_min = expf(2.0f * (dmin - 0.7f));
  const float ew_max = expf(2.0f * (dmax - 0.7f));
  const float inv_range = 1.0f / (ew_max - ew_min + 1e-6f);
  const float ew_bias = -ew_min * inv_range;

  dim3 grid(B * BLOCKS_PER_BATCH);  // 8192 blocks
  dim3 block(256);
  pizza_burn_kernel<<<grid, block, 0, stream>>>(img, u_xy, u_radius, u_intensity,
                                                u_burn, out, inv_range, ew_bias);
}